// Round 3
// baseline (747.662 us; speedup 1.0000x reference)
//
#include <hip/hip_runtime.h>
#include <math.h>

#define NB 8192
#define NIN 64
#define NOUT 128
#define NHID 32
#define NEXO 3
#define EXROWS 192
#define NTGT 2

__device__ __forceinline__ float sigmoidf(float x) {
    return 1.0f / (1.0f + __expf(-x));
}

// -------------------------------------------------------------------------
// Kernel A: exogenous contributions E[b,i,o] (includes b1+b3), written to out.
// Phase 1: thread (h=tid>>3, ic=tid&7) computes, for 16 i-positions,
//   sigmoid(W2[2+e][h] . window) folded immediately into c0/c1 via W3.
//   W2exo staged in LDS [96][68] (padded: h-lanes hit distinct banks).
// Reduce over h: 3 shfl_xor stages (8 h per wave) + LDS wave partials.
// Phase 3: thread i (<128) adds the W1.exog dot (W1 read wave-uniform from
//   global -> s_load) and writes E.
// -------------------------------------------------------------------------
__global__ __launch_bounds__(256, 4) void narx_exog_kernel(
    const float* __restrict__ exog,
    const float* __restrict__ W1, const float* __restrict__ b1,
    const float* __restrict__ W2, const float* __restrict__ b2,
    const float* __restrict__ W3, const float* __restrict__ b3,
    float* __restrict__ E)
{
    __shared__ __align__(16) float exs[NEXO][EXROWS];   // 2.25 KB
    __shared__ __align__(16) float w2l[96][68];         // 25.5 KB, padded stride
    __shared__ __align__(16) float w3l[2][96];          // exo columns of W3
    __shared__ __align__(16) float part[4][2][128];     // per-wave partials
    __shared__ float b2l[96];

    const int tid = threadIdx.x;
    const int b = blockIdx.x;
    const float* exb = exog + (size_t)b * (EXROWS * NEXO);

    // ---- staging ----
    for (int idx = tid; idx < EXROWS * NEXO; idx += 256) {
        int t = idx / 3;
        int e = idx - t * 3;
        exs[e][t] = exb[idx];
    }
    for (int idx = tid; idx < 96 * 16; idx += 256) {   // W2 exo rows as float4
        int u = idx >> 4, t4 = idx & 15;
        float4 g = *(const float4*)(W2 + ((size_t)(64 + u)) * NIN + t4 * 4);
        *(float4*)&w2l[u][t4 * 4] = g;
    }
    for (int idx = tid; idx < 192; idx += 256) {
        int o = idx / 96, u = idx - o * 96;
        w3l[o][u] = W3[o * 160 + 64 + u];
    }
    if (tid < 96) b2l[tid] = b2[64 + tid];
    __syncthreads();

    const int h  = tid >> 3;    // 0..31
    const int ic = tid & 7;     // 0..7
    const int i0 = ic * 16;

    float c0[16], c1[16];
    #pragma unroll
    for (int k = 0; k < 16; ++k) { c0[k] = 0.f; c1[k] = 0.f; }

    #pragma unroll 1
    for (int e = 0; e < NEXO; ++e) {
        const int u = e * NHID + h;
        const float bb = b2l[u];
        float acc[16];
        #pragma unroll
        for (int k = 0; k < 16; ++k) acc[k] = bb;

        float exw[16];
        #pragma unroll
        for (int i4 = 0; i4 < 4; ++i4) {
            float4 xv = *(const float4*)&exs[e][i0 + i4 * 4];
            exw[i4*4+0] = xv.x; exw[i4*4+1] = xv.y; exw[i4*4+2] = xv.z; exw[i4*4+3] = xv.w;
        }
        const float* wp = &w2l[u][0];
        #pragma unroll
        for (int tq = 0; tq < 16; ++tq) {
            float4 wv = *(const float4*)(wp + tq * 4);
            float4 xn = *(const float4*)&exs[e][i0 + 16 + tq * 4];
            #pragma unroll
            for (int dt = 0; dt < 4; ++dt) {
                const int t = tq * 4 + dt;
                const float wt = (dt == 0) ? wv.x : (dt == 1) ? wv.y : (dt == 2) ? wv.z : wv.w;
                #pragma unroll
                for (int ii = 0; ii < 16; ++ii)
                    acc[ii] += wt * exw[(t + ii) & 15];
                exw[t & 15] = (dt == 0) ? xn.x : (dt == 1) ? xn.y : (dt == 2) ? xn.z : xn.w;
            }
        }
        const float w3a = w3l[0][u];
        const float w3b = w3l[1][u];
        #pragma unroll
        for (int ii = 0; ii < 16; ++ii) {
            float sgv = sigmoidf(acc[ii]);
            c0[ii] += w3a * sgv;
            c1[ii] += w3b * sgv;
        }
    }

    // reduce over the 8 h-values within each wave (tid bits 3..5)
    #pragma unroll
    for (int k = 0; k < 16; ++k) {
        c0[k] += __shfl_xor(c0[k], 8, 64);
        c0[k] += __shfl_xor(c0[k], 16, 64);
        c0[k] += __shfl_xor(c0[k], 32, 64);
        c1[k] += __shfl_xor(c1[k], 8, 64);
        c1[k] += __shfl_xor(c1[k], 16, 64);
        c1[k] += __shfl_xor(c1[k], 32, 64);
    }
    if ((tid & 56) == 0) {      // one lane per (wave, ic)
        const int w = tid >> 6;
        #pragma unroll
        for (int k4 = 0; k4 < 4; ++k4) {
            float4 a = make_float4(c0[k4*4], c0[k4*4+1], c0[k4*4+2], c0[k4*4+3]);
            *(float4*)&part[w][0][i0 + k4 * 4] = a;
            float4 bq = make_float4(c1[k4*4], c1[k4*4+1], c1[k4*4+2], c1[k4*4+3]);
            *(float4*)&part[w][1][i0 + k4 * 4] = bq;
        }
    }
    __syncthreads();

    // ---- phase 3: W1 exog dot + assemble ----
    if (tid < 128) {
        const int i = tid;
        float v0 = b1[0] + b3[0];
        float v1 = b1[1] + b3[1];
        #pragma unroll
        for (int w = 0; w < 4; ++w) { v0 += part[w][0][i]; v1 += part[w][1][i]; }
        #pragma unroll 1
        for (int e = 0; e < NEXO; ++e) {
            #pragma unroll 8
            for (int t = 0; t < NIN; ++t) {
                float x = exs[e][i + t];
                v0 += W1[t * 5 + 2 + e] * x;          // uniform index -> s_load
                v1 += W1[320 + t * 5 + 2 + e] * x;
            }
        }
        float2 ev; ev.x = v0; ev.y = v1;
        *(float2*)&E[(size_t)b * (NOUT * NTGT) + i * 2] = ev;
    }
}

// -------------------------------------------------------------------------
// Kernel B: recurrence. ONE batch element per 64-thread block.
// Lane (s=tid>>5, h=tid&31) owns hidden unit (s,h); 72-deep register ring
// holds the window. 6-shuffle reduce (cross-half exchange + 5-stage
// butterfly). e2/ylds reads prefetched at step top.
// -------------------------------------------------------------------------
#define CH 8
#define WIN 72

__global__ __launch_bounds__(64, 3) void narx_recur_kernel(
    const float* __restrict__ target,
    const float* __restrict__ W1,
    const float* __restrict__ W2, const float* __restrict__ b2,
    const float* __restrict__ W3,
    float* __restrict__ out)   // holds E on entry; final preds on exit
{
    __shared__ __align__(16) float ylds[NTGT][EXROWS];
    __shared__ __align__(16) float e2[NOUT][NTGT];

    const int tid = threadIdx.x;
    const int b = blockIdx.x;
    const int s = tid >> 5;
    const int h = tid & 31;

    {
        float2 tv = *(const float2*)&target[(size_t)b * (NIN * NTGT) + tid * 2];
        ylds[0][tid] = tv.x;
        ylds[1][tid] = tv.y;
    }
    {
        float4 ev = *(const float4*)&out[(size_t)b * (NOUT * NTGT) + tid * 4];
        *(float4*)&(((float*)e2)[tid * 4]) = ev;
    }
    __syncthreads();

    float w2[NIN];
    const float* wr = W2 + (s * NHID + h) * NIN;
    #pragma unroll
    for (int t4 = 0; t4 < 16; ++t4) {
        float4 wv = *(const float4*)(wr + t4 * 4);
        w2[t4*4+0] = wv.x; w2[t4*4+1] = wv.y; w2[t4*4+2] = wv.z; w2[t4*4+3] = wv.w;
    }
    const float bb  = b2[s * NHID + h];
    const float w3a = W3[s * NHID + h];
    const float w3b = W3[160 + s * NHID + h];
    float w1a[2], w1b[2];
    #pragma unroll
    for (int dt = 0; dt < 2; ++dt) {
        w1a[dt] = W1[(2 * h + dt) * 5 + s];
        w1b[dt] = W1[320 + (2 * h + dt) * 5 + s];
    }

    float ywin[WIN];
    #pragma unroll
    for (int k = 0; k < NIN; ++k) ywin[k] = ylds[s][k];

    #pragma unroll 1
    for (int c = 0; c < NOUT / CH; ++c) {
        if (c > 0) {
            #pragma unroll
            for (int k = 0; k < NIN; ++k) ywin[k] = ywin[k + CH];
        }
        #pragma unroll
        for (int ci = 0; ci < CH; ++ci) {
            const int i = c * CH + ci;
            // prefetch LDS operands (latency hides under the dot)
            const float ev  = e2[i][s];
            const float y1a = ylds[s][i + 2 * h];
            const float y1b = ylds[s][i + 2 * h + 1];

            float ae = bb, ao = 0.f;
            #pragma unroll
            for (int t = 0; t < NIN; t += 2) {
                ae += w2[t]     * ywin[ci + t];
                ao += w2[t + 1] * ywin[ci + t + 1];
            }
            const float sg = sigmoidf(ae + ao);
            float v0 = w3a * sg + w1a[0] * y1a + w1a[1] * y1b;
            float v1 = w3b * sg + w1b[0] * y1a + w1b[1] * y1b;

            // cross-half exchange, then 5-stage butterfly within the half
            float vo = s ? v0 : v1;                  // value the OTHER half needs
            float cc = (s ? v1 : v0) + __shfl_xor(vo, 32, 64);
            cc += __shfl_xor(cc, 1, 64);
            cc += __shfl_xor(cc, 2, 64);
            cc += __shfl_xor(cc, 4, 64);
            cc += __shfl_xor(cc, 8, 64);
            cc += __shfl_xor(cc, 16, 64);

            const float pred = cc + ev + ywin[ci + 63];
            ywin[ci + 64] = pred;
            if (h == 0) {
                ylds[s][i + NIN] = pred;
                e2[i][s] = pred;
            }
        }
    }
    __syncthreads();
    {
        float4 ev = *(const float4*)&(((float*)e2)[tid * 4]);
        *(float4*)&out[(size_t)b * (NOUT * NTGT) + tid * 4] = ev;
    }
}

extern "C" void kernel_launch(void* const* d_in, const int* in_sizes, int n_in,
                              void* d_out, int out_size, void* d_ws, size_t ws_size,
                              hipStream_t stream) {
    (void)in_sizes; (void)n_in; (void)out_size; (void)d_ws; (void)ws_size;
    const float* target = (const float*)d_in[0];
    const float* exog   = (const float*)d_in[1];
    const float* W1     = (const float*)d_in[2];
    const float* b1     = (const float*)d_in[3];
    const float* W2     = (const float*)d_in[4];
    const float* b2     = (const float*)d_in[5];
    const float* W3     = (const float*)d_in[6];
    const float* b3     = (const float*)d_in[7];
    float* out = (float*)d_out;

    hipLaunchKernelGGL(narx_exog_kernel, dim3(NB), dim3(256), 0, stream,
                       exog, W1, b1, W2, b2, W3, b3, out);
    hipLaunchKernelGGL(narx_recur_kernel, dim3(NB), dim3(64), 0, stream,
                       target, W1, W2, b2, W3, out);
}

// Round 4
// 392.834 us; speedup vs baseline: 1.9033x; 1.9033x over previous
//
#include <hip/hip_runtime.h>
#include <math.h>

#define NB 8192
#define NIN 64
#define NOUT 128
#define NHID 32
#define NEXO 3
#define EXROWS 192
#define NTGT 2

__device__ __forceinline__ float sigmoidf(float x) {
    return 1.0f / (1.0f + __expf(-x));
}

// -------------------------------------------------------------------------
// Kernel A: exogenous contributions E[b,i,o] (includes b1+b3), written to out.
// Phase 1: thread (h=tid>>3, ic=tid&7) computes, for 16 i-positions,
//   sigmoid(W2[2+e][h] . window) folded immediately into c0/c1 via W3.
// Reduce over h: 3 shfl_xor stages + LDS wave partials.
// Phase 3: 2-way split (i=tid>>1, half=tid&1), W1-exog staged in LDS.
// -------------------------------------------------------------------------
__global__ __launch_bounds__(256, 4) void narx_exog_kernel(
    const float* __restrict__ exog,
    const float* __restrict__ W1, const float* __restrict__ b1,
    const float* __restrict__ W2, const float* __restrict__ b2,
    const float* __restrict__ W3, const float* __restrict__ b3,
    float* __restrict__ E)
{
    __shared__ __align__(16) float exs[NEXO][EXROWS];
    __shared__ __align__(16) float w2l[96][68];
    __shared__ __align__(16) float w3l[2][96];
    __shared__ __align__(16) float w1e[2][NEXO][NIN];   // W1 exog cols
    __shared__ __align__(16) float part[4][2][128];
    __shared__ float b2l[96];

    const int tid = threadIdx.x;
    const int b = blockIdx.x;
    const float* exb = exog + (size_t)b * (EXROWS * NEXO);

    for (int idx = tid; idx < EXROWS * NEXO; idx += 256) {
        int t = idx / 3;
        int e = idx - t * 3;
        exs[e][t] = exb[idx];
    }
    for (int idx = tid; idx < 96 * 16; idx += 256) {
        int u = idx >> 4, t4 = idx & 15;
        float4 g = *(const float4*)(W2 + ((size_t)(64 + u)) * NIN + t4 * 4);
        *(float4*)&w2l[u][t4 * 4] = g;
    }
    for (int idx = tid; idx < 192; idx += 256) {
        int o = idx / 96, u = idx - o * 96;
        w3l[o][u] = W3[o * 160 + 64 + u];
    }
    for (int idx = tid; idx < 384; idx += 256) {
        int o = idx / 192;
        int r = idx - o * 192;
        int e = r >> 6, t = r & 63;
        w1e[o][e][t] = W1[o * 320 + t * 5 + 2 + e];
    }
    if (tid < 96) b2l[tid] = b2[64 + tid];
    __syncthreads();

    const int h  = tid >> 3;
    const int ic = tid & 7;
    const int i0 = ic * 16;

    float c0[16], c1[16];
    #pragma unroll
    for (int k = 0; k < 16; ++k) { c0[k] = 0.f; c1[k] = 0.f; }

    #pragma unroll 1
    for (int e = 0; e < NEXO; ++e) {
        const int u = e * NHID + h;
        const float bb = b2l[u];
        float acc[16];
        #pragma unroll
        for (int k = 0; k < 16; ++k) acc[k] = bb;

        float exw[16];
        #pragma unroll
        for (int i4 = 0; i4 < 4; ++i4) {
            float4 xv = *(const float4*)&exs[e][i0 + i4 * 4];
            exw[i4*4+0] = xv.x; exw[i4*4+1] = xv.y; exw[i4*4+2] = xv.z; exw[i4*4+3] = xv.w;
        }
        const float* wp = &w2l[u][0];
        #pragma unroll
        for (int tq = 0; tq < 16; ++tq) {
            float4 wv = *(const float4*)(wp + tq * 4);
            float4 xn = *(const float4*)&exs[e][i0 + 16 + tq * 4];
            #pragma unroll
            for (int dt = 0; dt < 4; ++dt) {
                const int t = tq * 4 + dt;
                const float wt = (dt == 0) ? wv.x : (dt == 1) ? wv.y : (dt == 2) ? wv.z : wv.w;
                #pragma unroll
                for (int ii = 0; ii < 16; ++ii)
                    acc[ii] += wt * exw[(t + ii) & 15];
                exw[t & 15] = (dt == 0) ? xn.x : (dt == 1) ? xn.y : (dt == 2) ? xn.z : xn.w;
            }
        }
        const float w3a = w3l[0][u];
        const float w3b = w3l[1][u];
        #pragma unroll
        for (int ii = 0; ii < 16; ++ii) {
            float sgv = sigmoidf(acc[ii]);
            c0[ii] += w3a * sgv;
            c1[ii] += w3b * sgv;
        }
    }

    #pragma unroll
    for (int k = 0; k < 16; ++k) {
        c0[k] += __shfl_xor(c0[k], 8, 64);
        c0[k] += __shfl_xor(c0[k], 16, 64);
        c0[k] += __shfl_xor(c0[k], 32, 64);
        c1[k] += __shfl_xor(c1[k], 8, 64);
        c1[k] += __shfl_xor(c1[k], 16, 64);
        c1[k] += __shfl_xor(c1[k], 32, 64);
    }
    if ((tid & 56) == 0) {
        const int w = tid >> 6;
        #pragma unroll
        for (int k4 = 0; k4 < 4; ++k4) {
            float4 a = make_float4(c0[k4*4], c0[k4*4+1], c0[k4*4+2], c0[k4*4+3]);
            *(float4*)&part[w][0][i0 + k4 * 4] = a;
            float4 bq = make_float4(c1[k4*4], c1[k4*4+1], c1[k4*4+2], c1[k4*4+3]);
            *(float4*)&part[w][1][i0 + k4 * 4] = bq;
        }
    }
    __syncthreads();

    // phase 3: i = tid>>1, half = tid&1 splits t-range and partials
    {
        const int i = tid >> 1;
        const int half = tid & 1;
        float v0 = 0.f, v1 = 0.f;
        #pragma unroll
        for (int w = 0; w < 2; ++w) {
            v0 += part[half * 2 + w][0][i];
            v1 += part[half * 2 + w][1][i];
        }
        #pragma unroll 1
        for (int e = 0; e < NEXO; ++e) {
            #pragma unroll 8
            for (int k = 0; k < 32; ++k) {
                const int t = half * 32 + k;
                float x = exs[e][i + t];
                v0 += w1e[0][e][t] * x;
                v1 += w1e[1][e][t] * x;
            }
        }
        v0 += __shfl_xor(v0, 1, 64);
        v1 += __shfl_xor(v1, 1, 64);
        if (half == 0) {
            float2 ev;
            ev.x = v0 + b1[0] + b3[0];
            ev.y = v1 + b1[1] + b3[1];
            *(float2*)&E[(size_t)b * (NOUT * NTGT) + i * 2] = ev;
        }
    }
}

// -------------------------------------------------------------------------
// Kernel B: recurrence. 4 batch elements per 256-thread block, one per wave.
// Lane (s=l>>5, h=l&31) owns hidden unit (s,h). Window lives in a per-wave
// LDS slice (broadcast reads). Per 8-step chunk: stream the 64 known window
// values once into 8 partial dot accumulators P[ci] (static indices), then
// run the 8 sequential steps adding only the in-chunk pred tail terms.
// -------------------------------------------------------------------------
#define CH 8

__global__ __launch_bounds__(256) void narx_recur_kernel(
    const float* __restrict__ target,
    const float* __restrict__ W1,
    const float* __restrict__ W2, const float* __restrict__ b2,
    const float* __restrict__ W3,
    float* __restrict__ out)   // holds E on entry; final preds on exit
{
    __shared__ __align__(16) float y[4][NTGT][200];    // per-wave window, pad 200
    __shared__ __align__(16) float e2l[4][NOUT][NTGT]; // per-wave E copy

    const int tid = threadIdx.x;
    const int w = tid >> 6;            // wave -> batch within block
    const int l = tid & 63;            // lane
    const int s = l >> 5;              // series / output index
    const int h = l & 31;              // hidden unit
    const int b = blockIdx.x * 4 + w;

    {   // init window rows 0..63
        float2 tv = *(const float2*)&target[(size_t)b * (NIN * NTGT) + l * 2];
        y[w][0][l] = tv.x;
        y[w][1][l] = tv.y;
    }
    {   // E -> LDS
        float4 ev = *(const float4*)&out[(size_t)b * (NOUT * NTGT) + l * 4];
        *(float4*)&(((float*)&e2l[w][0][0])[l * 4]) = ev;
    }
    __syncthreads();

    // per-lane weights (registers)
    float w2[NIN];
    const float* wr = W2 + (s * NHID + h) * NIN;
    #pragma unroll
    for (int t4 = 0; t4 < 16; ++t4) {
        float4 wv = *(const float4*)(wr + t4 * 4);
        w2[t4*4+0] = wv.x; w2[t4*4+1] = wv.y; w2[t4*4+2] = wv.z; w2[t4*4+3] = wv.w;
    }
    const float bb  = b2[s * NHID + h];
    const float w3a = W3[s * NHID + h];
    const float w3b = W3[160 + s * NHID + h];
    float w1a[2], w1b[2];
    #pragma unroll
    for (int dt = 0; dt < 2; ++dt) {
        w1a[dt] = W1[(2 * h + dt) * 5 + s];
        w1b[dt] = W1[320 + (2 * h + dt) * 5 + s];
    }

    float* yw = &y[w][s][0];           // this half-wave's series row
    const float* e2w = &e2l[w][0][0];

    #pragma unroll 1
    for (int c = 0; c < NOUT / CH; ++c) {
        const int i0 = c * CH;

        // ---- stream precompute: P[ci] = bb + sum over known window ----
        float P[CH];
        #pragma unroll
        for (int j = 0; j < CH; ++j) P[j] = bb;
        float ylast = 0.f;
        #pragma unroll
        for (int kq = 0; kq < 16; ++kq) {
            float4 yv = *(const float4*)&yw[i0 + kq * 4];
            #pragma unroll
            for (int d = 0; d < 4; ++d) {
                const int k = kq * 4 + d;
                const float yk = (d == 0) ? yv.x : (d == 1) ? yv.y : (d == 2) ? yv.z : yv.w;
                #pragma unroll
                for (int ci = 0; ci < CH; ++ci) {
                    if (ci <= k) P[ci] += w2[k - ci] * yk;   // compile-time pruned
                }
                if (k == 63) ylast = yk;
            }
        }

        // ---- 8 sequential steps ----
        float predprev = ylast;
        #pragma unroll
        for (int ci = 0; ci < CH; ++ci) {
            const int i = i0 + ci;
            const float y1a = yw[i + 2 * h];
            const float y1b = yw[i + 2 * h + 1];
            const float ev  = e2w[i * 2 + s];

            const float sg = sigmoidf(P[ci]);
            float v0 = w3a * sg + w1a[0] * y1a + w1a[1] * y1b;
            float v1 = w3b * sg + w1b[0] * y1a + w1b[1] * y1b;

            float vo = s ? v0 : v1;
            float cc = (s ? v1 : v0) + __shfl_xor(vo, 32, 64);
            cc += __shfl_xor(cc, 1, 64);
            cc += __shfl_xor(cc, 2, 64);
            cc += __shfl_xor(cc, 4, 64);
            cc += __shfl_xor(cc, 8, 64);
            cc += __shfl_xor(cc, 16, 64);

            const float pred = cc + ev + predprev;
            #pragma unroll
            for (int cj = ci + 1; cj < CH; ++cj)
                P[cj] += w2[64 - (cj - ci)] * pred;   // tail terms, static idx
            if (h == 0) yw[i + 64] = pred;
            predprev = pred;
        }
    }

    // dump predictions: lane l covers i = 2l, 2l+1
    {
        float4 ov;
        ov.x = y[w][0][64 + 2 * l];
        ov.y = y[w][1][64 + 2 * l];
        ov.z = y[w][0][64 + 2 * l + 1];
        ov.w = y[w][1][64 + 2 * l + 1];
        *(float4*)&out[(size_t)b * (NOUT * NTGT) + l * 4] = ov;
    }
}

extern "C" void kernel_launch(void* const* d_in, const int* in_sizes, int n_in,
                              void* d_out, int out_size, void* d_ws, size_t ws_size,
                              hipStream_t stream) {
    (void)in_sizes; (void)n_in; (void)out_size; (void)d_ws; (void)ws_size;
    const float* target = (const float*)d_in[0];
    const float* exog   = (const float*)d_in[1];
    const float* W1     = (const float*)d_in[2];
    const float* b1     = (const float*)d_in[3];
    const float* W2     = (const float*)d_in[4];
    const float* b2     = (const float*)d_in[5];
    const float* W3     = (const float*)d_in[6];
    const float* b3     = (const float*)d_in[7];
    float* out = (float*)d_out;

    hipLaunchKernelGGL(narx_exog_kernel, dim3(NB), dim3(256), 0, stream,
                       exog, W1, b1, W2, b2, W3, b3, out);
    hipLaunchKernelGGL(narx_recur_kernel, dim3(NB / 4), dim3(256), 0, stream,
                       target, W1, W2, b2, W3, out);
}

// Round 5
// 274.379 us; speedup vs baseline: 2.7249x; 1.4317x over previous
//
#include <hip/hip_runtime.h>
#include <math.h>

#define NB 8192
#define NIN 64
#define NOUT 128
#define NHID 32
#define NEXO 3
#define EXROWS 192
#define NTGT 2

typedef float f32x4 __attribute__((ext_vector_type(4)));
typedef short bf16x8 __attribute__((ext_vector_type(8)));

__device__ __forceinline__ float sigmoidf(float x) {
    return 1.0f / (1.0f + __expf(-x));
}

__device__ __forceinline__ unsigned short f2bf(float x) {   // RNE float->bf16
    unsigned int u = __float_as_uint(x);
    unsigned int r = u + 0x7fffu + ((u >> 16) & 1u);
    return (unsigned short)(r >> 16);
}

// -------------------------------------------------------------------------
// Kernel A (MFMA): E[b,i,o] = b1+b3 + out1_exog + out2_exog, written to out.
// Per block: 1 batch. The 96-filter x 128-lag x 64-tap conv runs as bf16
// MFMA (A = W2 rows, B = Toeplitz windows via 8-replica shifted LDS).
// sigma-path bf16; direct out1 path stays fp32 (precision).
// Wave wv handles i in [wv*32, wv*32+32) (2 N-tiles).
// -------------------------------------------------------------------------
__global__ __launch_bounds__(256, 4) void narx_exog_kernel(
    const float* __restrict__ exog,
    const float* __restrict__ W1, const float* __restrict__ b1,
    const float* __restrict__ W2, const float* __restrict__ b2,
    const float* __restrict__ W3, const float* __restrict__ b3,
    float* __restrict__ E)
{
    __shared__ __align__(16) float exs[NEXO][EXROWS];           // fp32 signal
    __shared__ __align__(16) unsigned short exrep[NEXO * 8][200]; // bf16 replicas, exrep[e*8+r][q]=ex[e][q+r]
    __shared__ __align__(16) unsigned short w2bf[NEXO * 32][72];  // bf16 W2 exo rows
    __shared__ __align__(16) float2 w1e2[NEXO][NIN];            // (W1[0][t*5+2+e], W1[1][...])
    __shared__ __align__(16) float b2l[96];
    __shared__ __align__(16) float w3l[2][96];

    const int tid = threadIdx.x;
    const int b = blockIdx.x;
    const float* exb = exog + (size_t)b * (EXROWS * NEXO);

    // ---- stage fp32 signal + weights ----
    for (int idx = tid; idx < EXROWS * NEXO; idx += 256) {
        int t = idx / 3;
        int e = idx - t * 3;
        exs[e][t] = exb[idx];
    }
    for (int idx = tid; idx < 6144; idx += 256) {          // W2 exo -> bf16
        int e = idx >> 11;
        int rem = idx & 2047;
        int u = rem >> 6, t = rem & 63;
        w2bf[e * 32 + u][t] = f2bf(W2[(size_t)(64 + e * 32 + u) * NIN + t]);
    }
    for (int idx = tid; idx < 192; idx += 256) {           // W1 exog cols
        int e = idx >> 6, t = idx & 63;
        w1e2[e][t] = make_float2(W1[t * 5 + 2 + e], W1[320 + t * 5 + 2 + e]);
    }
    if (tid < 96)  b2l[tid] = b2[64 + tid];
    for (int idx = tid; idx < 192; idx += 256) {
        int o = idx / 96, u = idx - o * 96;
        w3l[o][u] = W3[o * 160 + 64 + u];
    }
    __syncthreads();

    // ---- build bf16 replicas from exs ----
    for (int idx = tid; idx < NEXO * 8 * 192; idx += 256) {
        int e = idx / 1536;
        int rem = idx - e * 1536;
        int r = rem / 192;
        int q = rem - r * 192;
        float v = (q + r < 192) ? exs[e][q + r] : 0.f;
        exrep[e * 8 + r][q] = f2bf(v);
    }
    __syncthreads();

    const int wv = tid >> 6;     // wave -> i-range
    const int l  = tid & 63;
    const int iw = wv * 32;
    const int lg = l >> 4;       // row/k group
    const int col = l & 15;

    float acc0[2] = {0.f, 0.f};
    float acc1[2] = {0.f, 0.f};

    #pragma unroll 1
    for (int e = 0; e < NEXO; ++e) {
        // per-row bias/W3 quads for this e (broadcast b128 reads)
        f32x4 b2v[2], w30v[2], w31v[2];
        #pragma unroll
        for (int mt = 0; mt < 2; ++mt) {
            b2v[mt]  = *(const f32x4*)&b2l[e * 32 + mt * 16 + lg * 4];
            w30v[mt] = *(const f32x4*)&w3l[0][e * 32 + mt * 16 + lg * 4];
            w31v[mt] = *(const f32x4*)&w3l[1][e * 32 + mt * 16 + lg * 4];
        }

        // ---- MFMA: C[u][i] = b2 + W2 . windows ----
        f32x4 cacc[2][2];
        #pragma unroll
        for (int mt = 0; mt < 2; ++mt)
            #pragma unroll
            for (int nt = 0; nt < 2; ++nt)
                cacc[mt][nt] = b2v[mt];

        #pragma unroll
        for (int kt = 0; kt < 2; ++kt) {
            bf16x8 af[2], bfr[2];
            #pragma unroll
            for (int mt = 0; mt < 2; ++mt)
                af[mt] = *(const bf16x8*)&w2bf[e * 32 + mt * 16 + col][kt * 32 + lg * 8];
            #pragma unroll
            for (int nt = 0; nt < 2; ++nt)
                bfr[nt] = *(const bf16x8*)&exrep[e * 8 + (l & 7)]
                              [iw + nt * 16 + kt * 32 + lg * 8 + ((l >> 3) & 1) * 8];
            #pragma unroll
            for (int mt = 0; mt < 2; ++mt)
                #pragma unroll
                for (int nt = 0; nt < 2; ++nt)
                    cacc[mt][nt] = __builtin_amdgcn_mfma_f32_16x16x32_bf16(
                        af[mt], bfr[nt], cacc[mt][nt], 0, 0, 0);
        }

        // ---- sigmoid fold (rows u = e*32 + mt*16 + lg*4 + r) ----
        #pragma unroll
        for (int mt = 0; mt < 2; ++mt)
            #pragma unroll
            for (int nt = 0; nt < 2; ++nt) {
                #pragma unroll
                for (int r = 0; r < 4; ++r) {
                    float sg = sigmoidf(cacc[mt][nt][r]);
                    acc0[nt] += w30v[mt][r] * sg;
                    acc1[nt] += w31v[mt][r] * sg;
                }
            }

        // ---- out1 direct path, fp32 (group lg covers t in [lg*16, lg*16+16)) ----
        const float* exs_e = &exs[e][0];
        #pragma unroll
        for (int dt = 0; dt < 16; ++dt) {
            float2 wv2 = w1e2[e][lg * 16 + dt];
            float x0 = exs_e[iw + l + dt];          // i = iw + col, t = lg*16+dt -> addr = iw + l + dt
            float x1 = exs_e[iw + 16 + l + dt];
            acc0[0] += wv2.x * x0;
            acc1[0] += wv2.y * x0;
            acc0[1] += wv2.x * x1;
            acc1[1] += wv2.y * x1;
        }
    }

    // ---- reduce across the 4 lane-groups, store ----
    #pragma unroll
    for (int nt = 0; nt < 2; ++nt) {
        acc0[nt] += __shfl_xor(acc0[nt], 16, 64);
        acc0[nt] += __shfl_xor(acc0[nt], 32, 64);
        acc1[nt] += __shfl_xor(acc1[nt], 16, 64);
        acc1[nt] += __shfl_xor(acc1[nt], 32, 64);
    }
    if (lg == 0) {
        const float bias0 = b1[0] + b3[0];
        const float bias1 = b1[1] + b3[1];
        #pragma unroll
        for (int nt = 0; nt < 2; ++nt) {
            int i = iw + nt * 16 + col;
            *(float2*)&E[(size_t)b * (NOUT * NTGT) + i * 2] =
                make_float2(acc0[nt] + bias0, acc1[nt] + bias1);
        }
    }
}

// -------------------------------------------------------------------------
// Kernel B: recurrence (unchanged from round 4). 4 batches per block, one
// per wave; chunked P-precompute + 8 sequential steps per chunk.
// -------------------------------------------------------------------------
#define CH 8

__global__ __launch_bounds__(256) void narx_recur_kernel(
    const float* __restrict__ target,
    const float* __restrict__ W1,
    const float* __restrict__ W2, const float* __restrict__ b2,
    const float* __restrict__ W3,
    float* __restrict__ out)
{
    __shared__ __align__(16) float y[4][NTGT][200];
    __shared__ __align__(16) float e2l[4][NOUT][NTGT];

    const int tid = threadIdx.x;
    const int w = tid >> 6;
    const int l = tid & 63;
    const int s = l >> 5;
    const int h = l & 31;
    const int b = blockIdx.x * 4 + w;

    {
        float2 tv = *(const float2*)&target[(size_t)b * (NIN * NTGT) + l * 2];
        y[w][0][l] = tv.x;
        y[w][1][l] = tv.y;
    }
    {
        float4 ev = *(const float4*)&out[(size_t)b * (NOUT * NTGT) + l * 4];
        *(float4*)&(((float*)&e2l[w][0][0])[l * 4]) = ev;
    }
    __syncthreads();

    float w2[NIN];
    const float* wr = W2 + (s * NHID + h) * NIN;
    #pragma unroll
    for (int t4 = 0; t4 < 16; ++t4) {
        float4 wv = *(const float4*)(wr + t4 * 4);
        w2[t4*4+0] = wv.x; w2[t4*4+1] = wv.y; w2[t4*4+2] = wv.z; w2[t4*4+3] = wv.w;
    }
    const float bb  = b2[s * NHID + h];
    const float w3a = W3[s * NHID + h];
    const float w3b = W3[160 + s * NHID + h];
    float w1a[2], w1b[2];
    #pragma unroll
    for (int dt = 0; dt < 2; ++dt) {
        w1a[dt] = W1[(2 * h + dt) * 5 + s];
        w1b[dt] = W1[320 + (2 * h + dt) * 5 + s];
    }

    float* yw = &y[w][s][0];
    const float* e2w = &e2l[w][0][0];

    #pragma unroll 1
    for (int c = 0; c < NOUT / CH; ++c) {
        const int i0 = c * CH;

        float P[CH];
        #pragma unroll
        for (int j = 0; j < CH; ++j) P[j] = bb;
        float ylast = 0.f;
        #pragma unroll
        for (int kq = 0; kq < 16; ++kq) {
            float4 yv = *(const float4*)&yw[i0 + kq * 4];
            #pragma unroll
            for (int d = 0; d < 4; ++d) {
                const int k = kq * 4 + d;
                const float yk = (d == 0) ? yv.x : (d == 1) ? yv.y : (d == 2) ? yv.z : yv.w;
                #pragma unroll
                for (int ci = 0; ci < CH; ++ci) {
                    if (ci <= k) P[ci] += w2[k - ci] * yk;
                }
                if (k == 63) ylast = yk;
            }
        }

        float predprev = ylast;
        #pragma unroll
        for (int ci = 0; ci < CH; ++ci) {
            const int i = i0 + ci;
            const float y1a = yw[i + 2 * h];
            const float y1b = yw[i + 2 * h + 1];
            const float ev  = e2w[i * 2 + s];

            const float sg = sigmoidf(P[ci]);
            float v0 = w3a * sg + w1a[0] * y1a + w1a[1] * y1b;
            float v1 = w3b * sg + w1b[0] * y1a + w1b[1] * y1b;

            float vo = s ? v0 : v1;
            float cc = (s ? v1 : v0) + __shfl_xor(vo, 32, 64);
            cc += __shfl_xor(cc, 1, 64);
            cc += __shfl_xor(cc, 2, 64);
            cc += __shfl_xor(cc, 4, 64);
            cc += __shfl_xor(cc, 8, 64);
            cc += __shfl_xor(cc, 16, 64);

            const float pred = cc + ev + predprev;
            #pragma unroll
            for (int cj = ci + 1; cj < CH; ++cj)
                P[cj] += w2[64 - (cj - ci)] * pred;
            if (h == 0) yw[i + 64] = pred;
            predprev = pred;
        }
    }

    {
        float4 ov;
        ov.x = y[w][0][64 + 2 * l];
        ov.y = y[w][1][64 + 2 * l];
        ov.z = y[w][0][64 + 2 * l + 1];
        ov.w = y[w][1][64 + 2 * l + 1];
        *(float4*)&out[(size_t)b * (NOUT * NTGT) + l * 4] = ov;
    }
}

extern "C" void kernel_launch(void* const* d_in, const int* in_sizes, int n_in,
                              void* d_out, int out_size, void* d_ws, size_t ws_size,
                              hipStream_t stream) {
    (void)in_sizes; (void)n_in; (void)out_size; (void)d_ws; (void)ws_size;
    const float* target = (const float*)d_in[0];
    const float* exog   = (const float*)d_in[1];
    const float* W1     = (const float*)d_in[2];
    const float* b1     = (const float*)d_in[3];
    const float* W2     = (const float*)d_in[4];
    const float* b2     = (const float*)d_in[5];
    const float* W3     = (const float*)d_in[6];
    const float* b3     = (const float*)d_in[7];
    float* out = (float*)d_out;

    hipLaunchKernelGGL(narx_exog_kernel, dim3(NB), dim3(256), 0, stream,
                       exog, W1, b1, W2, b2, W3, b3, out);
    hipLaunchKernelGGL(narx_recur_kernel, dim3(NB / 4), dim3(256), 0, stream,
                       target, W1, W2, b2, W3, out);
}

// Round 6
// 259.653 us; speedup vs baseline: 2.8795x; 1.0567x over previous
//
#include <hip/hip_runtime.h>
#include <math.h>

#define NB 8192
#define NIN 64
#define NOUT 128
#define NHID 32
#define NEXO 3
#define EXROWS 192
#define NTGT 2

typedef float f32x4 __attribute__((ext_vector_type(4)));
typedef short bf16x8 __attribute__((ext_vector_type(8)));

__device__ __forceinline__ float sigmoidf(float x) {
    return 1.0f / (1.0f + __expf(-x));
}

__device__ __forceinline__ unsigned short f2bf(float x) {   // RNE float->bf16
    unsigned int u = __float_as_uint(x);
    unsigned int r = u + 0x7fffu + ((u >> 16) & 1u);
    return (unsigned short)(r >> 16);
}

// DPP-based cross-lane add (VALU pipe, no LDS traffic).
// CTRL: 0xB1 = quad_perm[1,0,3,2] (xor1), 0x4E = quad_perm[2,3,0,1] (xor2),
//       0x141 = row_half_mirror (xor7), 0x128 = row_ror:8 (xor8 within 16).
template<int CTRL>
__device__ __forceinline__ float dpp_add(float x) {
    int p = __builtin_amdgcn_update_dpp(0, __float_as_int(x), CTRL, 0xf, 0xf, true);
    return x + __int_as_float(p);
}
__device__ __forceinline__ float swz_add_xor16(float x) {   // ds_swizzle xor16
    int p = __builtin_amdgcn_ds_swizzle(__float_as_int(x), 0x401f);
    return x + __int_as_float(p);
}

// -------------------------------------------------------------------------
// Kernel A (MFMA): E[b,i,o] = b1+b3 + out1_exog + out2_exog, written to out.
// (unchanged from round 5)
// -------------------------------------------------------------------------
__global__ __launch_bounds__(256, 4) void narx_exog_kernel(
    const float* __restrict__ exog,
    const float* __restrict__ W1, const float* __restrict__ b1,
    const float* __restrict__ W2, const float* __restrict__ b2,
    const float* __restrict__ W3, const float* __restrict__ b3,
    float* __restrict__ E)
{
    __shared__ __align__(16) float exs[NEXO][EXROWS];
    __shared__ __align__(16) unsigned short exrep[NEXO * 8][200];
    __shared__ __align__(16) unsigned short w2bf[NEXO * 32][72];
    __shared__ __align__(16) float2 w1e2[NEXO][NIN];
    __shared__ __align__(16) float b2l[96];
    __shared__ __align__(16) float w3l[2][96];

    const int tid = threadIdx.x;
    const int b = blockIdx.x;
    const float* exb = exog + (size_t)b * (EXROWS * NEXO);

    for (int idx = tid; idx < EXROWS * NEXO; idx += 256) {
        int t = idx / 3;
        int e = idx - t * 3;
        exs[e][t] = exb[idx];
    }
    for (int idx = tid; idx < 6144; idx += 256) {
        int e = idx >> 11;
        int rem = idx & 2047;
        int u = rem >> 6, t = rem & 63;
        w2bf[e * 32 + u][t] = f2bf(W2[(size_t)(64 + e * 32 + u) * NIN + t]);
    }
    for (int idx = tid; idx < 192; idx += 256) {
        int e = idx >> 6, t = idx & 63;
        w1e2[e][t] = make_float2(W1[t * 5 + 2 + e], W1[320 + t * 5 + 2 + e]);
    }
    if (tid < 96)  b2l[tid] = b2[64 + tid];
    for (int idx = tid; idx < 192; idx += 256) {
        int o = idx / 96, u = idx - o * 96;
        w3l[o][u] = W3[o * 160 + 64 + u];
    }
    __syncthreads();

    for (int idx = tid; idx < NEXO * 8 * 192; idx += 256) {
        int e = idx / 1536;
        int rem = idx - e * 1536;
        int r = rem / 192;
        int q = rem - r * 192;
        float v = (q + r < 192) ? exs[e][q + r] : 0.f;
        exrep[e * 8 + r][q] = f2bf(v);
    }
    __syncthreads();

    const int wv = tid >> 6;
    const int l  = tid & 63;
    const int iw = wv * 32;
    const int lg = l >> 4;
    const int col = l & 15;

    float acc0[2] = {0.f, 0.f};
    float acc1[2] = {0.f, 0.f};

    #pragma unroll 1
    for (int e = 0; e < NEXO; ++e) {
        f32x4 b2v[2], w30v[2], w31v[2];
        #pragma unroll
        for (int mt = 0; mt < 2; ++mt) {
            b2v[mt]  = *(const f32x4*)&b2l[e * 32 + mt * 16 + lg * 4];
            w30v[mt] = *(const f32x4*)&w3l[0][e * 32 + mt * 16 + lg * 4];
            w31v[mt] = *(const f32x4*)&w3l[1][e * 32 + mt * 16 + lg * 4];
        }

        f32x4 cacc[2][2];
        #pragma unroll
        for (int mt = 0; mt < 2; ++mt)
            #pragma unroll
            for (int nt = 0; nt < 2; ++nt)
                cacc[mt][nt] = b2v[mt];

        #pragma unroll
        for (int kt = 0; kt < 2; ++kt) {
            bf16x8 af[2], bfr[2];
            #pragma unroll
            for (int mt = 0; mt < 2; ++mt)
                af[mt] = *(const bf16x8*)&w2bf[e * 32 + mt * 16 + col][kt * 32 + lg * 8];
            #pragma unroll
            for (int nt = 0; nt < 2; ++nt)
                bfr[nt] = *(const bf16x8*)&exrep[e * 8 + (l & 7)]
                              [iw + nt * 16 + kt * 32 + lg * 8 + ((l >> 3) & 1) * 8];
            #pragma unroll
            for (int mt = 0; mt < 2; ++mt)
                #pragma unroll
                for (int nt = 0; nt < 2; ++nt)
                    cacc[mt][nt] = __builtin_amdgcn_mfma_f32_16x16x32_bf16(
                        af[mt], bfr[nt], cacc[mt][nt], 0, 0, 0);
        }

        #pragma unroll
        for (int mt = 0; mt < 2; ++mt)
            #pragma unroll
            for (int nt = 0; nt < 2; ++nt) {
                #pragma unroll
                for (int r = 0; r < 4; ++r) {
                    float sg = sigmoidf(cacc[mt][nt][r]);
                    acc0[nt] += w30v[mt][r] * sg;
                    acc1[nt] += w31v[mt][r] * sg;
                }
            }

        const float* exs_e = &exs[e][0];
        #pragma unroll
        for (int dt = 0; dt < 16; ++dt) {
            float2 wv2 = w1e2[e][lg * 16 + dt];
            float x0 = exs_e[iw + l + dt];
            float x1 = exs_e[iw + 16 + l + dt];
            acc0[0] += wv2.x * x0;
            acc1[0] += wv2.y * x0;
            acc0[1] += wv2.x * x1;
            acc1[1] += wv2.y * x1;
        }
    }

    #pragma unroll
    for (int nt = 0; nt < 2; ++nt) {
        acc0[nt] += __shfl_xor(acc0[nt], 16, 64);
        acc0[nt] += __shfl_xor(acc0[nt], 32, 64);
        acc1[nt] += __shfl_xor(acc1[nt], 16, 64);
        acc1[nt] += __shfl_xor(acc1[nt], 32, 64);
    }
    if (lg == 0) {
        const float bias0 = b1[0] + b3[0];
        const float bias1 = b1[1] + b3[1];
        #pragma unroll
        for (int nt = 0; nt < 2; ++nt) {
            int i = iw + nt * 16 + col;
            *(float2*)&E[(size_t)b * (NOUT * NTGT) + i * 2] =
                make_float2(acc0[nt] + bias0, acc1[nt] + bias1);
        }
    }
}

// -------------------------------------------------------------------------
// Kernel B: recurrence. 4 batches per 256-thread block, one per wave.
// Chunked precompute (as round 5) + per-step reduce rebuilt on the VALU:
// fold(shfl32) -> xor16 (ds_swizzle) -> xor8/xor7/xor2/xor1 (DPP adds).
// Masks {1,2,7,8,16} generate the full 32-group (no double counting).
// E values prefetched per chunk as broadcast float4 reads.
// -------------------------------------------------------------------------
#define CH 8

__global__ __launch_bounds__(256) void narx_recur_kernel(
    const float* __restrict__ target,
    const float* __restrict__ W1,
    const float* __restrict__ W2, const float* __restrict__ b2,
    const float* __restrict__ W3,
    float* __restrict__ out)
{
    __shared__ __align__(16) float y[4][NTGT][200];
    __shared__ __align__(16) float e2l[4][NOUT][NTGT];

    const int tid = threadIdx.x;
    const int w = tid >> 6;
    const int l = tid & 63;
    const int s = l >> 5;
    const int h = l & 31;
    const int b = blockIdx.x * 4 + w;

    {
        float2 tv = *(const float2*)&target[(size_t)b * (NIN * NTGT) + l * 2];
        y[w][0][l] = tv.x;
        y[w][1][l] = tv.y;
    }
    {
        float4 ev = *(const float4*)&out[(size_t)b * (NOUT * NTGT) + l * 4];
        *(float4*)&(((float*)&e2l[w][0][0])[l * 4]) = ev;
    }
    __syncthreads();

    float w2[NIN];
    const float* wr = W2 + (s * NHID + h) * NIN;
    #pragma unroll
    for (int t4 = 0; t4 < 16; ++t4) {
        float4 wv = *(const float4*)(wr + t4 * 4);
        w2[t4*4+0] = wv.x; w2[t4*4+1] = wv.y; w2[t4*4+2] = wv.z; w2[t4*4+3] = wv.w;
    }
    const float bb  = b2[s * NHID + h];
    const float w3a = W3[s * NHID + h];
    const float w3b = W3[160 + s * NHID + h];
    float w1a[2], w1b[2];
    #pragma unroll
    for (int dt = 0; dt < 2; ++dt) {
        w1a[dt] = W1[(2 * h + dt) * 5 + s];
        w1b[dt] = W1[320 + (2 * h + dt) * 5 + s];
    }

    float* yw = &y[w][s][0];
    const float* e2w = &e2l[w][0][0];

    #pragma unroll 1
    for (int c = 0; c < NOUT / CH; ++c) {
        const int i0 = c * CH;

        // ---- prefetch E for the 8 steps of this chunk (broadcast b128) ----
        float ev8[CH];
        #pragma unroll
        for (int q = 0; q < 4; ++q) {
            float4 e4 = *(const float4*)&e2w[i0 * 2 + q * 4];
            ev8[2 * q]     = s ? e4.y : e4.x;
            ev8[2 * q + 1] = s ? e4.w : e4.z;
        }

        // ---- stream precompute: P[ci] = bb + sum over known window ----
        float P[CH];
        #pragma unroll
        for (int j = 0; j < CH; ++j) P[j] = bb;
        float ylast = 0.f;
        #pragma unroll
        for (int kq = 0; kq < 16; ++kq) {
            float4 yv = *(const float4*)&yw[i0 + kq * 4];
            #pragma unroll
            for (int d = 0; d < 4; ++d) {
                const int k = kq * 4 + d;
                const float yk = (d == 0) ? yv.x : (d == 1) ? yv.y : (d == 2) ? yv.z : yv.w;
                #pragma unroll
                for (int ci = 0; ci < CH; ++ci) {
                    if (ci <= k) P[ci] += w2[k - ci] * yk;
                }
                if (k == 63) ylast = yk;
            }
        }

        // ---- 8 sequential steps ----
        float predprev = ylast;
        #pragma unroll
        for (int ci = 0; ci < CH; ++ci) {
            const int i = i0 + ci;
            const float y1a = yw[i + 2 * h];
            const float y1b = yw[i + 2 * h + 1];

            const float sg = sigmoidf(P[ci]);
            float v0 = w3a * sg + w1a[0] * y1a + w1a[1] * y1b;
            float v1 = w3b * sg + w1b[0] * y1a + w1b[1] * y1b;

            // cross-half fold (LDS), then xor16 (LDS swizzle), then DPP (VALU)
            float vo = s ? v0 : v1;
            float cc = (s ? v1 : v0) + __shfl_xor(vo, 32, 64);
            cc = swz_add_xor16(cc);       // xor 16
            cc = dpp_add<0x128>(cc);      // xor 8  (row_ror:8)
            cc = dpp_add<0x141>(cc);      // xor 7  (row_half_mirror)
            cc = dpp_add<0x4E>(cc);       // xor 2  (quad_perm [2,3,0,1])
            cc = dpp_add<0xB1>(cc);       // xor 1  (quad_perm [1,0,3,2])

            const float pred = cc + ev8[ci] + predprev;
            #pragma unroll
            for (int cj = ci + 1; cj < CH; ++cj)
                P[cj] += w2[64 - (cj - ci)] * pred;
            if (h == 0) yw[i + 64] = pred;
            predprev = pred;
        }
    }

    {
        float4 ov;
        ov.x = y[w][0][64 + 2 * l];
        ov.y = y[w][1][64 + 2 * l];
        ov.z = y[w][0][64 + 2 * l + 1];
        ov.w = y[w][1][64 + 2 * l + 1];
        *(float4*)&out[(size_t)b * (NOUT * NTGT) + l * 4] = ov;
    }
}

extern "C" void kernel_launch(void* const* d_in, const int* in_sizes, int n_in,
                              void* d_out, int out_size, void* d_ws, size_t ws_size,
                              hipStream_t stream) {
    (void)in_sizes; (void)n_in; (void)out_size; (void)d_ws; (void)ws_size;
    const float* target = (const float*)d_in[0];
    const float* exog   = (const float*)d_in[1];
    const float* W1     = (const float*)d_in[2];
    const float* b1     = (const float*)d_in[3];
    const float* W2     = (const float*)d_in[4];
    const float* b2     = (const float*)d_in[5];
    const float* W3     = (const float*)d_in[6];
    const float* b3     = (const float*)d_in[7];
    float* out = (float*)d_out;

    hipLaunchKernelGGL(narx_exog_kernel, dim3(NB), dim3(256), 0, stream,
                       exog, W1, b1, W2, b2, W3, b3, out);
    hipLaunchKernelGGL(narx_recur_kernel, dim3(NB / 4), dim3(256), 0, stream,
                       target, W1, W2, b2, W3, out);
}